// Round 2
// baseline (457.147 us; speedup 1.0000x reference)
//
#include <hip/hip_runtime.h>
#include <hip/hip_bf16.h>

typedef __attribute__((ext_vector_type(8))) __bf16 bf16x8;
typedef __attribute__((ext_vector_type(8))) unsigned short us8;
typedef __attribute__((ext_vector_type(4))) float f32x4;

#define N_TOK 8192
#define EMB 1024

static __device__ __forceinline__ unsigned short f2bf(float f) {
  union { float f; unsigned int u; } c; c.f = f;
  unsigned int u = c.u;
  u = (u + 0x7fffu + ((u >> 16) & 1u)) >> 16;  // RNE
  return (unsigned short)u;
}

static __device__ __forceinline__ f32x4 mfma16(bf16x8 a, bf16x8 b, f32x4 c) {
  return __builtin_amdgcn_mfma_f32_16x16x32_bf16(a, b, c, 0, 0, 0);
}

// C[m][n] = sum_k A[m][k] * W[n][k] + bias[n]
// A: [M][K] (fp32 or bf16), W: [N][K] fp32. OUT_TRANS: out[n*ldout+m] else out[m*ldout+n].
template<bool A_BF16, bool OUT_BF16, bool OUT_TRANS>
__global__ __launch_bounds__(256) void gemm_xt(
    const void* __restrict__ Aptr, const float* __restrict__ W,
    const float* __restrict__ bias, void* __restrict__ outp,
    int M, int N, int K, int ldout)
{
  __shared__ __align__(16) unsigned short As[128][40];
  __shared__ __align__(16) unsigned short Bs[128][40];

  const int tid  = threadIdx.x;
  const int lane = tid & 63;
  const int wv   = tid >> 6;
  const int wrb  = (wv >> 1) * 64;   // wave row base within tile
  const int wcb  = (wv & 1) * 64;    // wave col base within tile
  const long brow = (long)blockIdx.y * 128;
  const long bcol = (long)blockIdx.x * 128;

  const int srow = tid >> 1;         // staging row 0..127
  const int skc  = (tid & 1) * 16;   // staging k-chunk 0/16
  const int r16  = lane & 15;
  const int kq   = (lane >> 4) * 8;
  const int rq   = (lane >> 4) * 4;

  const f32x4 zz = {0.f, 0.f, 0.f, 0.f};
  f32x4 acc[4][4];
#pragma unroll
  for (int i = 0; i < 4; ++i)
#pragma unroll
    for (int j = 0; j < 4; ++j) acc[i][j] = zz;

  for (int k0 = 0; k0 < K; k0 += 32) {
    __syncthreads();
    // ---- stage A tile (128 x 32) ----
    if (A_BF16) {
      const unsigned short* Ab = (const unsigned short*)Aptr + (brow + srow) * (long)K + k0 + skc;
      *(us8*)&As[srow][skc]     = *(const us8*)Ab;
      *(us8*)&As[srow][skc + 8] = *(const us8*)(Ab + 8);
    } else {
      const float* Af = (const float*)Aptr + (brow + srow) * (long)K + k0 + skc;
      float4 f0 = *(const float4*)(Af);
      float4 f1 = *(const float4*)(Af + 4);
      float4 f2 = *(const float4*)(Af + 8);
      float4 f3 = *(const float4*)(Af + 12);
      us8 p0, p1;
      p0[0]=f2bf(f0.x); p0[1]=f2bf(f0.y); p0[2]=f2bf(f0.z); p0[3]=f2bf(f0.w);
      p0[4]=f2bf(f1.x); p0[5]=f2bf(f1.y); p0[6]=f2bf(f1.z); p0[7]=f2bf(f1.w);
      p1[0]=f2bf(f2.x); p1[1]=f2bf(f2.y); p1[2]=f2bf(f2.z); p1[3]=f2bf(f2.w);
      p1[4]=f2bf(f3.x); p1[5]=f2bf(f3.y); p1[6]=f2bf(f3.z); p1[7]=f2bf(f3.w);
      *(us8*)&As[srow][skc]     = p0;
      *(us8*)&As[srow][skc + 8] = p1;
    }
    // ---- stage B tile = W rows (128 x 32), fp32 always ----
    {
      const float* Wf = W + (bcol + srow) * (long)K + k0 + skc;
      float4 f0 = *(const float4*)(Wf);
      float4 f1 = *(const float4*)(Wf + 4);
      float4 f2 = *(const float4*)(Wf + 8);
      float4 f3 = *(const float4*)(Wf + 12);
      us8 p0, p1;
      p0[0]=f2bf(f0.x); p0[1]=f2bf(f0.y); p0[2]=f2bf(f0.z); p0[3]=f2bf(f0.w);
      p0[4]=f2bf(f1.x); p0[5]=f2bf(f1.y); p0[6]=f2bf(f1.z); p0[7]=f2bf(f1.w);
      p1[0]=f2bf(f2.x); p1[1]=f2bf(f2.y); p1[2]=f2bf(f2.z); p1[3]=f2bf(f2.w);
      p1[4]=f2bf(f3.x); p1[5]=f2bf(f3.y); p1[6]=f2bf(f3.z); p1[7]=f2bf(f3.w);
      *(us8*)&Bs[srow][skc]     = p0;
      *(us8*)&Bs[srow][skc + 8] = p1;
    }
    __syncthreads();

    bf16x8 av[4], bv_[4];
#pragma unroll
    for (int mi = 0; mi < 4; ++mi) av[mi]  = *(const bf16x8*)&As[wrb + mi*16 + r16][kq];
#pragma unroll
    for (int ni = 0; ni < 4; ++ni) bv_[ni] = *(const bf16x8*)&Bs[wcb + ni*16 + r16][kq];
#pragma unroll
    for (int mi = 0; mi < 4; ++mi)
#pragma unroll
      for (int ni = 0; ni < 4; ++ni)
        acc[mi][ni] = mfma16(av[mi], bv_[ni], acc[mi][ni]);
  }

  // ---- epilogue: D layout col=lane&15, row=4*(lane>>4)+reg ----
#pragma unroll
  for (int ni = 0; ni < 4; ++ni) {
    const long col = bcol + wcb + ni*16 + r16;
    const float bval = bias[col];
#pragma unroll
    for (int mi = 0; mi < 4; ++mi)
#pragma unroll
      for (int jr = 0; jr < 4; ++jr) {
        const long row = brow + wrb + mi*16 + rq + jr;
        const float v = acc[mi][ni][jr] + bval;
        const long oidx = OUT_TRANS ? col * (long)ldout + row : row * (long)ldout + col;
        if (OUT_BF16) ((unsigned short*)outp)[oidx] = f2bf(v);
        else          ((float*)outp)[oidx] = v;
      }
  }
}

// Flash attention over a dilated subsequence of length 2048 (m), d=64, causal.
// Qp/Kp: [N_TOK][EMB] bf16 (head h at cols h*64..h*64+63). Vt: [EMB][N_TOK] bf16 (transposed).
// AO: [N_TOK][EMB] bf16 output, pre-zeroed.
__global__ __launch_bounds__(256) void attn_dilated(
    const unsigned short* __restrict__ Qp, const unsigned short* __restrict__ Kp,
    const unsigned short* __restrict__ Vt, unsigned short* __restrict__ AO,
    int head_base, int seg_len, int dil, int off)
{
  __shared__ __align__(16) unsigned short Qs[64][72];
  __shared__ __align__(16) unsigned short Ks[64][72];
  __shared__ __align__(16) unsigned short Vs[64][72];  // Vs[d][key]
  __shared__ __align__(16) unsigned short Ps[64][72];

  const int qtile = blockIdx.x;             // 0..31 (m/64)
  const int h     = head_base + blockIdx.y; // head
  const long segb = (long)blockIdx.z * seg_len;
  const int h64   = h * 64;

  const int tid  = threadIdx.x;
  const int lane = tid & 63;
  const int wv   = tid >> 6;        // wave 0..3, owns q rows wv*16..wv*16+15
  const int r16  = lane & 15;
  const int kq   = (lane >> 4) * 8;
  const int rq   = (lane >> 4) * 4;

  // load Q tile (64 rows x 64 d)
  {
    const int row = tid >> 2;
    const int ds  = (tid & 3) * 16;
    const long grow = segb + off + (long)dil * (qtile * 64 + row);
    const unsigned short* src = Qp + grow * EMB + h64 + ds;
    *(us8*)&Qs[row][ds]     = *(const us8*)src;
    *(us8*)&Qs[row][ds + 8] = *(const us8*)(src + 8);
  }

  float m_run[4] = {-1e30f, -1e30f, -1e30f, -1e30f};
  float l_run[4] = {0.f, 0.f, 0.f, 0.f};
  const f32x4 zz = {0.f, 0.f, 0.f, 0.f};
  f32x4 o_acc[4];
#pragma unroll
  for (int dt = 0; dt < 4; ++dt) o_acc[dt] = zz;

  for (int j = 0; j <= qtile; ++j) {
    __syncthreads();  // previous iteration done reading Ks/Vs
    {
      const int row = tid >> 2;
      const int cs  = (tid & 3) * 16;
      const long gk = segb + off + (long)dil * (j * 64 + row);
      const unsigned short* ksrc = Kp + gk * EMB + h64 + cs;
      *(us8*)&Ks[row][cs]     = *(const us8*)ksrc;
      *(us8*)&Ks[row][cs + 8] = *(const us8*)(ksrc + 8);
      // V transposed tile: Vs[d=row][keys cs..cs+15]
      const unsigned short* vbase = Vt + (long)(h64 + row) * N_TOK + segb + off;
      if (dil == 1) {
        const unsigned short* vsrc = vbase + j * 64 + cs;
        *(us8*)&Vs[row][cs]     = *(const us8*)vsrc;
        *(us8*)&Vs[row][cs + 8] = *(const us8*)(vsrc + 8);
      } else {
#pragma unroll
        for (int q2 = 0; q2 < 16; ++q2)
          Vs[row][cs + q2] = vbase[(long)dil * (j * 64 + cs + q2)];
      }
    }
    __syncthreads();  // tiles ready

    // S = Q K^T : wave's 16 rows x 64 cols
    f32x4 st[4];
    bf16x8 aq0 = *(const bf16x8*)&Qs[wv*16 + r16][kq];
    bf16x8 aq1 = *(const bf16x8*)&Qs[wv*16 + r16][32 + kq];
#pragma unroll
    for (int nt = 0; nt < 4; ++nt) {
      f32x4 c = zz;
      bf16x8 b0 = *(const bf16x8*)&Ks[nt*16 + r16][kq];
      bf16x8 b1 = *(const bf16x8*)&Ks[nt*16 + r16][32 + kq];
      c = mfma16(aq0, b0, c);
      c = mfma16(aq1, b1, c);
      st[nt] = c;
    }

    // scale + causal mask (dilated-index space)
    // D layout: col(key) = nt*16 + r16, row(q, local to 64-row tile) = wv*16 + rq + jr
    const bool diag = (j == qtile);
#pragma unroll
    for (int nt = 0; nt < 4; ++nt)
#pragma unroll
      for (int jr = 0; jr < 4; ++jr) {
        float v = st[nt][jr] * 0.125f;  // 1/sqrt(64)
        if (diag && (nt*16 + r16 > wv*16 + rq + jr)) v = -1e30f;  // FIXED: include wv*16
        st[nt][jr] = v;
      }

    // online softmax: rows live in reg index jr, cols across 16 lanes x 4 nt
#pragma unroll
    for (int jr = 0; jr < 4; ++jr) {
      float mx = fmaxf(fmaxf(st[0][jr], st[1][jr]), fmaxf(st[2][jr], st[3][jr]));
#pragma unroll
      for (int sm = 1; sm < 16; sm <<= 1) mx = fmaxf(mx, __shfl_xor(mx, sm, 64));
      const float mnew  = fmaxf(m_run[jr], mx);
      const float alpha = __expf(m_run[jr] - mnew);
      float psum = 0.f;
#pragma unroll
      for (int nt = 0; nt < 4; ++nt) {
        const float p = __expf(st[nt][jr] - mnew);
        st[nt][jr] = p;
        psum += p;
      }
#pragma unroll
      for (int sm = 1; sm < 16; sm <<= 1) psum += __shfl_xor(psum, sm, 64);
      l_run[jr] = l_run[jr] * alpha + psum;
      m_run[jr] = mnew;
#pragma unroll
      for (int dt = 0; dt < 4; ++dt) o_acc[dt][jr] *= alpha;
    }

    // P -> bf16 into wave-private LDS slice
#pragma unroll
    for (int nt = 0; nt < 4; ++nt)
#pragma unroll
      for (int jr = 0; jr < 4; ++jr)
        Ps[wv*16 + rq + jr][nt*16 + r16] = f2bf(st[nt][jr]);

    __syncthreads();  // conservative: P visible (wave-private anyway)

    // O += P @ V
#pragma unroll
    for (int kk = 0; kk < 2; ++kk) {
      bf16x8 pa = *(const bf16x8*)&Ps[wv*16 + r16][kk*32 + kq];
#pragma unroll
      for (int dt = 0; dt < 4; ++dt) {
        bf16x8 vb = *(const bf16x8*)&Vs[dt*16 + r16][kk*32 + kq];
        o_acc[dt] = mfma16(pa, vb, o_acc[dt]);
      }
    }
  }

  // normalize + scatter to AO
#pragma unroll
  for (int jr = 0; jr < 4; ++jr) {
    const float inv = 1.f / l_run[jr];
    const int row_l = wv*16 + rq + jr;
    const long grow = segb + off + (long)dil * (qtile*64 + row_l);
    unsigned short* dst = AO + grow * EMB + h64 + r16;
#pragma unroll
    for (int dt = 0; dt < 4; ++dt)
      dst[dt*16] = f2bf(o_acc[dt][jr] * inv);
  }
}

extern "C" void kernel_launch(void* const* d_in, const int* in_sizes, int n_in,
                              void* d_out, int out_size, void* d_ws, size_t ws_size,
                              hipStream_t stream) {
  const float* query = (const float*)d_in[0];
  const float* key_  = (const float*)d_in[1];
  const float* value = (const float*)d_in[2];
  const float* Wq = (const float*)d_in[3];
  const float* bq = (const float*)d_in[4];
  const float* Wk = (const float*)d_in[5];
  const float* bk = (const float*)d_in[6];
  const float* Wv = (const float*)d_in[7];
  const float* bv = (const float*)d_in[8];
  const float* Wo = (const float*)d_in[9];
  const float* bo = (const float*)d_in[10];

  // workspace layout (bf16): Qp, Kp, Vt (transposed [EMB][N_TOK]), AO  = 4 x 16 MiB
  unsigned short* Qp = (unsigned short*)d_ws;
  unsigned short* Kp = Qp + (size_t)N_TOK * EMB;
  unsigned short* Vt = Kp + (size_t)N_TOK * EMB;
  unsigned short* AO = Vt + (size_t)N_TOK * EMB;

  dim3 blk(256);
  dim3 ggrid(EMB / 128, N_TOK / 128);

  hipLaunchKernelGGL((gemm_xt<false, true, false>), ggrid, blk, 0, stream,
                     (const void*)query, Wq, bq, (void*)Qp, N_TOK, EMB, EMB, EMB);
  hipLaunchKernelGGL((gemm_xt<false, true, false>), ggrid, blk, 0, stream,
                     (const void*)key_, Wk, bk, (void*)Kp, N_TOK, EMB, EMB, EMB);
  hipLaunchKernelGGL((gemm_xt<false, true, true>), ggrid, blk, 0, stream,
                     (const void*)value, Wv, bv, (void*)Vt, N_TOK, EMB, EMB, N_TOK);

  hipMemsetAsync(AO, 0, (size_t)N_TOK * EMB * 2, stream);

  // group 0: heads 0-7, seg 2048, dilation 1, offset 0, 4 segments
  hipLaunchKernelGGL(attn_dilated, dim3(32, 8, 4), blk, 0, stream,
                     Qp, Kp, Vt, AO, 0, 2048, 1, 0);
  // group 1: heads 8-15, seg 4096, dilation 2, offset 1, 2 segments
  hipLaunchKernelGGL(attn_dilated, dim3(32, 8, 2), blk, 0, stream,
                     Qp, Kp, Vt, AO, 8, 4096, 2, 1);

  hipLaunchKernelGGL((gemm_xt<true, false, false>), ggrid, blk, 0, stream,
                     (const void*)AO, Wo, bo, d_out, N_TOK, EMB, EMB, EMB);
}

// Round 3
// 375.024 us; speedup vs baseline: 1.2190x; 1.2190x over previous
//
#include <hip/hip_runtime.h>
#include <hip/hip_bf16.h>

typedef __attribute__((ext_vector_type(8))) __bf16 bf16x8;
typedef __attribute__((ext_vector_type(8))) unsigned short us8;
typedef __attribute__((ext_vector_type(4))) float f32x4;

#define N_TOK 8192
#define EMB 1024

static __device__ __forceinline__ unsigned short f2bf(float f) {
  union { float f; unsigned int u; } c; c.f = f;
  unsigned int u = c.u;
  u = (u + 0x7fffu + ((u >> 16) & 1u)) >> 16;  // RNE
  return (unsigned short)u;
}

static __device__ __forceinline__ f32x4 mfma16(bf16x8 a, bf16x8 b, f32x4 c) {
  return __builtin_amdgcn_mfma_f32_16x16x32_bf16(a, b, c, 0, 0, 0);
}

// ---------------- fused QKV projection ----------------
// z=0: Q = X0 @ W0^T + b0 -> O0 [N_TOK][EMB] bf16
// z=1: K                  -> O1 [N_TOK][EMB] bf16
// z=2: V -> O2 transposed [EMB][N_TOK] bf16, with group-1 (feature>=512)
//      token remap: p -> (p odd ? p>>1 : 2048 + (p>>1)) within each 4096-seg.
__global__ __launch_bounds__(256) void qkv_gemm(
    const float* __restrict__ X0, const float* __restrict__ X1, const float* __restrict__ X2,
    const float* __restrict__ W0, const float* __restrict__ W1, const float* __restrict__ W2,
    const float* __restrict__ b0, const float* __restrict__ b1, const float* __restrict__ b2,
    unsigned short* __restrict__ O0, unsigned short* __restrict__ O1, unsigned short* __restrict__ O2)
{
  __shared__ __align__(16) unsigned short As[128][40];
  __shared__ __align__(16) unsigned short Bs[128][40];

  const int z = blockIdx.z;
  const float* X = (z == 0) ? X0 : (z == 1) ? X1 : X2;
  const float* W = (z == 0) ? W0 : (z == 1) ? W1 : W2;
  const float* bias = (z == 0) ? b0 : (z == 1) ? b1 : b2;

  const int tid  = threadIdx.x;
  const int lane = tid & 63;
  const int wv   = tid >> 6;
  const int wrb  = (wv >> 1) * 64;
  const int wcb  = (wv & 1) * 64;
  const long brow = (long)blockIdx.y * 128;
  const long bcol = (long)blockIdx.x * 128;

  const int srow = tid >> 1;
  const int skc  = (tid & 1) * 16;
  const int r16  = lane & 15;
  const int kq   = (lane >> 4) * 8;
  const int rq   = (lane >> 4) * 4;

  const f32x4 zz = {0.f, 0.f, 0.f, 0.f};
  f32x4 acc[4][4];
#pragma unroll
  for (int i = 0; i < 4; ++i)
#pragma unroll
    for (int j = 0; j < 4; ++j) acc[i][j] = zz;

  for (int k0 = 0; k0 < EMB; k0 += 32) {
    __syncthreads();
    {
      const float* Af = X + (brow + srow) * (long)EMB + k0 + skc;
      float4 f0 = *(const float4*)(Af);
      float4 f1 = *(const float4*)(Af + 4);
      float4 f2 = *(const float4*)(Af + 8);
      float4 f3 = *(const float4*)(Af + 12);
      us8 p0, p1;
      p0[0]=f2bf(f0.x); p0[1]=f2bf(f0.y); p0[2]=f2bf(f0.z); p0[3]=f2bf(f0.w);
      p0[4]=f2bf(f1.x); p0[5]=f2bf(f1.y); p0[6]=f2bf(f1.z); p0[7]=f2bf(f1.w);
      p1[0]=f2bf(f2.x); p1[1]=f2bf(f2.y); p1[2]=f2bf(f2.z); p1[3]=f2bf(f2.w);
      p1[4]=f2bf(f3.x); p1[5]=f2bf(f3.y); p1[6]=f2bf(f3.z); p1[7]=f2bf(f3.w);
      *(us8*)&As[srow][skc]     = p0;
      *(us8*)&As[srow][skc + 8] = p1;
    }
    {
      const float* Wf = W + (bcol + srow) * (long)EMB + k0 + skc;
      float4 f0 = *(const float4*)(Wf);
      float4 f1 = *(const float4*)(Wf + 4);
      float4 f2 = *(const float4*)(Wf + 8);
      float4 f3 = *(const float4*)(Wf + 12);
      us8 p0, p1;
      p0[0]=f2bf(f0.x); p0[1]=f2bf(f0.y); p0[2]=f2bf(f0.z); p0[3]=f2bf(f0.w);
      p0[4]=f2bf(f1.x); p0[5]=f2bf(f1.y); p0[6]=f2bf(f1.z); p0[7]=f2bf(f1.w);
      p1[0]=f2bf(f2.x); p1[1]=f2bf(f2.y); p1[2]=f2bf(f2.z); p1[3]=f2bf(f2.w);
      p1[4]=f2bf(f3.x); p1[5]=f2bf(f3.y); p1[6]=f2bf(f3.z); p1[7]=f2bf(f3.w);
      *(us8*)&Bs[srow][skc]     = p0;
      *(us8*)&Bs[srow][skc + 8] = p1;
    }
    __syncthreads();

    bf16x8 av[4], bv_[4];
#pragma unroll
    for (int mi = 0; mi < 4; ++mi) av[mi]  = *(const bf16x8*)&As[wrb + mi*16 + r16][kq];
#pragma unroll
    for (int ni = 0; ni < 4; ++ni) bv_[ni] = *(const bf16x8*)&Bs[wcb + ni*16 + r16][kq];
#pragma unroll
    for (int mi = 0; mi < 4; ++mi)
#pragma unroll
      for (int ni = 0; ni < 4; ++ni)
        acc[mi][ni] = mfma16(av[mi], bv_[ni], acc[mi][ni]);
  }

#pragma unroll
  for (int ni = 0; ni < 4; ++ni) {
    const long col = bcol + wcb + ni*16 + r16;
    const float bval = bias[col];
#pragma unroll
    for (int mi = 0; mi < 4; ++mi)
#pragma unroll
      for (int jr = 0; jr < 4; ++jr) {
        const long row = brow + wrb + mi*16 + rq + jr;
        const float v = acc[mi][ni][jr] + bval;
        if (z == 2) {
          long r = row;
          if (col >= 512) {  // group-1 heads: odd tokens first within each 4096-seg
            const long seg = row >> 12;
            const long p = row & 4095;
            r = (seg << 12) + ((p & 1) ? (p >> 1) : 2048 + (p >> 1));
          }
          O2[col * (long)N_TOK + r] = f2bf(v);
        } else {
          unsigned short* O = (z == 0) ? O0 : O1;
          O[row * (long)EMB + col] = f2bf(v);
        }
      }
  }
}

// ---------------- merged dilated flash attention ----------------
// blockIdx.z: 0..3 -> group0 (seg 2048, dil 1, off 0, heads 0-7)
//             4..5 -> group1 (seg 4096, dil 2, off 1, heads 8-15; V pre-gathered)
// QBLK=128 (4 waves x 32 rows), KVBLK=64.
__global__ __launch_bounds__(256) void attn_dilated2(
    const unsigned short* __restrict__ Qp, const unsigned short* __restrict__ Kp,
    const unsigned short* __restrict__ Vt, unsigned short* __restrict__ AO)
{
  __shared__ __align__(16) unsigned short Ks[64][72];
  __shared__ __align__(16) unsigned short Vs[64][72];   // Vs[d][key]
  __shared__ __align__(16) unsigned short Ps[128][72];

  const int z   = blockIdx.z;
  const int g1  = (z >= 4);
  const int dil = g1 ? 2 : 1;
  const int off = g1 ? 1 : 0;
  const long segb = g1 ? (long)(z - 4) * 4096 : (long)z * 2048;
  const int h   = (g1 ? 8 : 0) + blockIdx.y;
  const int h64 = h * 64;

  const int qtile = 15 - (int)blockIdx.x;  // long blocks dispatch first
  const int tid  = threadIdx.x;
  const int lane = tid & 63;
  const int wv   = tid >> 6;               // wave owns q rows wv*32 .. wv*32+31
  const int r16  = lane & 15;
  const int kq   = (lane >> 4) * 8;
  const int rq   = (lane >> 4) * 4;

  // Q -> registers (A-fragments), once
  bf16x8 aq[2][2];
#pragma unroll
  for (int mi = 0; mi < 2; ++mi) {
    const long grow = segb + off + (long)dil * (qtile * 128 + wv * 32 + mi * 16 + r16);
    const unsigned short* qsrc = Qp + grow * EMB + h64;
    aq[mi][0] = *(const bf16x8*)(qsrc + kq);
    aq[mi][1] = *(const bf16x8*)(qsrc + 32 + kq);
  }

  const f32x4 zz = {0.f, 0.f, 0.f, 0.f};
  f32x4 o_acc[2][4];
  float m_run[2][4], l_run[2][4];
#pragma unroll
  for (int mi = 0; mi < 2; ++mi)
#pragma unroll
    for (int t = 0; t < 4; ++t) {
      o_acc[mi][t] = zz;
      m_run[mi][t] = -1e30f;
      l_run[mi][t] = 0.f;
    }

  const int srow = tid >> 2;
  const int scs  = (tid & 3) * 16;
  const int jmax = 2 * qtile + 1;

  for (int j = 0; j <= jmax; ++j) {
    __syncthreads();  // prev iter done reading Ks/Vs
    {
      const long gk = segb + off + (long)dil * (j * 64 + srow);
      const unsigned short* ksrc = Kp + gk * EMB + h64 + scs;
      *(us8*)&Ks[srow][scs]     = *(const us8*)ksrc;
      *(us8*)&Ks[srow][scs + 8] = *(const us8*)(ksrc + 8);
      const unsigned short* vsrc = Vt + (long)(h64 + srow) * N_TOK + segb + j * 64 + scs;
      *(us8*)&Vs[srow][scs]     = *(const us8*)vsrc;
      *(us8*)&Vs[srow][scs + 8] = *(const us8*)(vsrc + 8);
    }
    __syncthreads();  // tiles ready

    const bool diagz = (j >= 2 * qtile);
#pragma unroll
    for (int mi = 0; mi < 2; ++mi) {
      // S = Q K^T : 32 rows (2 mi-tiles handled separately) x 64 keys
      f32x4 st[4];
#pragma unroll
      for (int nt = 0; nt < 4; ++nt) {
        bf16x8 bk0 = *(const bf16x8*)&Ks[nt*16 + r16][kq];
        bf16x8 bk1 = *(const bf16x8*)&Ks[nt*16 + r16][32 + kq];
        st[nt] = mfma16(aq[mi][1], bk1, mfma16(aq[mi][0], bk0, zz));
      }

#pragma unroll
      for (int nt = 0; nt < 4; ++nt)
#pragma unroll
        for (int jr = 0; jr < 4; ++jr) {
          float v = st[nt][jr] * 0.125f;
          if (diagz && (j*64 + nt*16 + r16 > qtile*128 + wv*32 + mi*16 + rq + jr))
            v = -1e30f;
          st[nt][jr] = v;
        }

      // online softmax (rows in jr, cols across 16 lanes x 4 nt)
#pragma unroll
      for (int jr = 0; jr < 4; ++jr) {
        float mx = fmaxf(fmaxf(st[0][jr], st[1][jr]), fmaxf(st[2][jr], st[3][jr]));
#pragma unroll
        for (int sm = 1; sm < 16; sm <<= 1) mx = fmaxf(mx, __shfl_xor(mx, sm, 64));
        const float mnew  = fmaxf(m_run[mi][jr], mx);
        const float alpha = __expf(m_run[mi][jr] - mnew);
        float psum = 0.f;
#pragma unroll
        for (int nt = 0; nt < 4; ++nt) {
          const float p = __expf(st[nt][jr] - mnew);
          st[nt][jr] = p;
          psum += p;
        }
#pragma unroll
        for (int sm = 1; sm < 16; sm <<= 1) psum += __shfl_xor(psum, sm, 64);
        l_run[mi][jr] = l_run[mi][jr] * alpha + psum;
        m_run[mi][jr] = mnew;
#pragma unroll
        for (int dt = 0; dt < 4; ++dt) o_acc[mi][dt][jr] *= alpha;
      }

      // P -> bf16, wave-private LDS rows (no barrier needed: same-wave order)
#pragma unroll
      for (int nt = 0; nt < 4; ++nt)
#pragma unroll
        for (int jr = 0; jr < 4; ++jr)
          Ps[wv*32 + mi*16 + rq + jr][nt*16 + r16] = f2bf(st[nt][jr]);
    }

    // O += P @ V
#pragma unroll
    for (int mi = 0; mi < 2; ++mi)
#pragma unroll
      for (int kk = 0; kk < 2; ++kk) {
        bf16x8 pa = *(const bf16x8*)&Ps[wv*32 + mi*16 + r16][kk*32 + kq];
#pragma unroll
        for (int dt = 0; dt < 4; ++dt) {
          bf16x8 vb = *(const bf16x8*)&Vs[dt*16 + r16][kk*32 + kq];
          o_acc[mi][dt] = mfma16(pa, vb, o_acc[mi][dt]);
        }
      }
  }

  // epilogue
#pragma unroll
  for (int mi = 0; mi < 2; ++mi)
#pragma unroll
    for (int jr = 0; jr < 4; ++jr) {
      const float inv = 1.f / l_run[mi][jr];
      const int row_l = wv*32 + mi*16 + rq + jr;
      const long grow = segb + off + (long)dil * (qtile*128 + row_l);
      unsigned short* dst = AO + grow * EMB + h64 + r16;
#pragma unroll
      for (int dt = 0; dt < 4; ++dt)
        dst[dt*16] = f2bf(o_acc[mi][dt][jr] * inv);
    }
}

// ---------------- output projection (unchanged) ----------------
__global__ __launch_bounds__(256) void gemm_out(
    const unsigned short* __restrict__ A, const float* __restrict__ W,
    const float* __restrict__ bias, float* __restrict__ outp)
{
  __shared__ __align__(16) unsigned short As[128][40];
  __shared__ __align__(16) unsigned short Bs[128][40];

  const int tid  = threadIdx.x;
  const int lane = tid & 63;
  const int wv   = tid >> 6;
  const int wrb  = (wv >> 1) * 64;
  const int wcb  = (wv & 1) * 64;
  const long brow = (long)blockIdx.y * 128;
  const long bcol = (long)blockIdx.x * 128;

  const int srow = tid >> 1;
  const int skc  = (tid & 1) * 16;
  const int r16  = lane & 15;
  const int kq   = (lane >> 4) * 8;
  const int rq   = (lane >> 4) * 4;

  const f32x4 zz = {0.f, 0.f, 0.f, 0.f};
  f32x4 acc[4][4];
#pragma unroll
  for (int i = 0; i < 4; ++i)
#pragma unroll
    for (int j = 0; j < 4; ++j) acc[i][j] = zz;

  for (int k0 = 0; k0 < EMB; k0 += 32) {
    __syncthreads();
    {
      const unsigned short* Ab = A + (brow + srow) * (long)EMB + k0 + skc;
      *(us8*)&As[srow][skc]     = *(const us8*)Ab;
      *(us8*)&As[srow][skc + 8] = *(const us8*)(Ab + 8);
    }
    {
      const float* Wf = W + (bcol + srow) * (long)EMB + k0 + skc;
      float4 f0 = *(const float4*)(Wf);
      float4 f1 = *(const float4*)(Wf + 4);
      float4 f2 = *(const float4*)(Wf + 8);
      float4 f3 = *(const float4*)(Wf + 12);
      us8 p0, p1;
      p0[0]=f2bf(f0.x); p0[1]=f2bf(f0.y); p0[2]=f2bf(f0.z); p0[3]=f2bf(f0.w);
      p0[4]=f2bf(f1.x); p0[5]=f2bf(f1.y); p0[6]=f2bf(f1.z); p0[7]=f2bf(f1.w);
      p1[0]=f2bf(f2.x); p1[1]=f2bf(f2.y); p1[2]=f2bf(f2.z); p1[3]=f2bf(f2.w);
      p1[4]=f2bf(f3.x); p1[5]=f2bf(f3.y); p1[6]=f2bf(f3.z); p1[7]=f2bf(f3.w);
      *(us8*)&Bs[srow][skc]     = p0;
      *(us8*)&Bs[srow][skc + 8] = p1;
    }
    __syncthreads();

    bf16x8 av[4], bv_[4];
#pragma unroll
    for (int mi = 0; mi < 4; ++mi) av[mi]  = *(const bf16x8*)&As[wrb + mi*16 + r16][kq];
#pragma unroll
    for (int ni = 0; ni < 4; ++ni) bv_[ni] = *(const bf16x8*)&Bs[wcb + ni*16 + r16][kq];
#pragma unroll
    for (int mi = 0; mi < 4; ++mi)
#pragma unroll
      for (int ni = 0; ni < 4; ++ni)
        acc[mi][ni] = mfma16(av[mi], bv_[ni], acc[mi][ni]);
  }

#pragma unroll
  for (int ni = 0; ni < 4; ++ni) {
    const long col = bcol + wcb + ni*16 + r16;
    const float bval = bias[col];
#pragma unroll
    for (int mi = 0; mi < 4; ++mi)
#pragma unroll
      for (int jr = 0; jr < 4; ++jr) {
        const long row = brow + wrb + mi*16 + rq + jr;
        outp[row * (long)EMB + col] = acc[mi][ni][jr] + bval;
      }
  }
}

extern "C" void kernel_launch(void* const* d_in, const int* in_sizes, int n_in,
                              void* d_out, int out_size, void* d_ws, size_t ws_size,
                              hipStream_t stream) {
  const float* query = (const float*)d_in[0];
  const float* key_  = (const float*)d_in[1];
  const float* value = (const float*)d_in[2];
  const float* Wq = (const float*)d_in[3];
  const float* bq = (const float*)d_in[4];
  const float* Wk = (const float*)d_in[5];
  const float* bk = (const float*)d_in[6];
  const float* Wv = (const float*)d_in[7];
  const float* bv = (const float*)d_in[8];
  const float* Wo = (const float*)d_in[9];
  const float* bo = (const float*)d_in[10];

  unsigned short* Qp = (unsigned short*)d_ws;
  unsigned short* Kp = Qp + (size_t)N_TOK * EMB;
  unsigned short* Vt = Kp + (size_t)N_TOK * EMB;   // [EMB][N_TOK], group1 token-remapped
  unsigned short* AO = Vt + (size_t)N_TOK * EMB;

  dim3 blk(256);

  hipLaunchKernelGGL(qkv_gemm, dim3(EMB/128, N_TOK/128, 3), blk, 0, stream,
                     query, key_, value, Wq, Wk, Wv, bq, bk, bv, Qp, Kp, Vt);

  hipMemsetAsync(AO, 0, (size_t)N_TOK * EMB * 2, stream);

  hipLaunchKernelGGL(attn_dilated2, dim3(16, 8, 6), blk, 0, stream, Qp, Kp, Vt, AO);

  hipLaunchKernelGGL(gemm_out, dim3(EMB/128, N_TOK/128), blk, 0, stream,
                     AO, Wo, bo, (float*)d_out);
}

// Round 4
// 317.872 us; speedup vs baseline: 1.4381x; 1.1798x over previous
//
#include <hip/hip_runtime.h>
#include <hip/hip_bf16.h>

typedef __attribute__((ext_vector_type(8))) __bf16 bf16x8;
typedef __attribute__((ext_vector_type(8))) unsigned short us8;
typedef __attribute__((ext_vector_type(4))) float f32x4;

#define N_TOK 8192
#define EMB 1024

static __device__ __forceinline__ unsigned short f2bf(float f) {
  union { float f; unsigned int u; } c; c.f = f;
  unsigned int u = c.u;
  u = (u + 0x7fffu + ((u >> 16) & 1u)) >> 16;  // RNE
  return (unsigned short)u;
}

static __device__ __forceinline__ f32x4 mfma16(bf16x8 a, bf16x8 b, f32x4 c) {
  return __builtin_amdgcn_mfma_f32_16x16x32_bf16(a, b, c, 0, 0, 0);
}

// ---------------- weight fp32 -> bf16 conversion (Wq,Wk,Wv,Wo) ----------------
__global__ __launch_bounds__(256) void wconv(
    const float* __restrict__ W0, const float* __restrict__ W1,
    const float* __restrict__ W2, const float* __restrict__ W3,
    unsigned short* __restrict__ O)
{
  const float* W = (blockIdx.y == 0) ? W0 : (blockIdx.y == 1) ? W1 :
                   (blockIdx.y == 2) ? W2 : W3;
  unsigned short* o = O + (size_t)blockIdx.y * EMB * EMB;
  const int base = (blockIdx.x * 256 + threadIdx.x) * 16;
  float4 f0 = *(const float4*)(W + base);
  float4 f1 = *(const float4*)(W + base + 4);
  float4 f2 = *(const float4*)(W + base + 8);
  float4 f3 = *(const float4*)(W + base + 12);
  us8 p0, p1;
  p0[0]=f2bf(f0.x); p0[1]=f2bf(f0.y); p0[2]=f2bf(f0.z); p0[3]=f2bf(f0.w);
  p0[4]=f2bf(f1.x); p0[5]=f2bf(f1.y); p0[6]=f2bf(f1.z); p0[7]=f2bf(f1.w);
  p1[0]=f2bf(f2.x); p1[1]=f2bf(f2.y); p1[2]=f2bf(f2.z); p1[3]=f2bf(f2.w);
  p1[4]=f2bf(f3.x); p1[5]=f2bf(f3.y); p1[6]=f2bf(f3.z); p1[7]=f2bf(f3.w);
  *(us8*)(o + base)     = p0;
  *(us8*)(o + base + 8) = p1;
}

// ---------------- fused QKV projection (A fp32, W bf16, prefetched) ----------------
// z=0: Q -> O0 [N_TOK][EMB]; z=1: K -> O1; z=2: V -> O2 transposed [EMB][N_TOK]
//   with group-1 (feature>=512) token remap p -> (p odd ? p>>1 : 2048+(p>>1)) per 4096-seg.
__global__ __launch_bounds__(256) void qkv_gemm2(
    const float* __restrict__ Xq, const float* __restrict__ Xk, const float* __restrict__ Xv,
    const unsigned short* __restrict__ Wb,   // 3 bf16 matrices, stride EMB*EMB
    const float* __restrict__ bq, const float* __restrict__ bk, const float* __restrict__ bv,
    unsigned short* __restrict__ O0, unsigned short* __restrict__ O1, unsigned short* __restrict__ O2)
{
  __shared__ __align__(16) unsigned short As[128][40];
  __shared__ __align__(16) unsigned short Bs[128][40];

  const int z = blockIdx.z;
  const float* X = (z == 0) ? Xq : (z == 1) ? Xk : Xv;
  const unsigned short* W = Wb + (size_t)z * EMB * EMB;
  const float* bias = (z == 0) ? bq : (z == 1) ? bk : bv;

  // bijective XCD-chunked swizzle: nwg=512 per z, 8 XCDs, 64-block chunks.
  // XCD c owns an 8x8 block-tile: A-panel reused 8x back-to-back, W L2-resident.
  const int lin  = blockIdx.x;
  const int work = (lin & 7) * 64 + (lin >> 3);
  const long brow = (long)(work >> 3) * 128;
  const long bcol = (long)(work & 7) * 128;

  const int tid  = threadIdx.x;
  const int lane = tid & 63;
  const int wv   = tid >> 6;
  const int wrb  = (wv >> 1) * 64;
  const int wcb  = (wv & 1) * 64;

  const int srow = tid >> 1;
  const int skc  = (tid & 1) * 16;
  const int r16  = lane & 15;
  const int kq   = (lane >> 4) * 8;
  const int rq   = (lane >> 4) * 4;

  const float* Aaddr = X + (brow + srow) * (long)EMB + skc;
  const unsigned short* Baddr = W + (bcol + srow) * (long)EMB + skc;

  const f32x4 zz = {0.f, 0.f, 0.f, 0.f};
  f32x4 acc[4][4];
#pragma unroll
  for (int i = 0; i < 4; ++i)
#pragma unroll
    for (int j = 0; j < 4; ++j) acc[i][j] = zz;

  // prefetch tile 0
  float4 a0 = *(const float4*)(Aaddr);
  float4 a1 = *(const float4*)(Aaddr + 4);
  float4 a2 = *(const float4*)(Aaddr + 8);
  float4 a3 = *(const float4*)(Aaddr + 12);
  us8 b0 = *(const us8*)(Baddr);
  us8 b1 = *(const us8*)(Baddr + 8);

  for (int k0 = 0; k0 < EMB; k0 += 32) {
    __syncthreads();  // LDS consumers of previous tile done
    {
      us8 p0, p1;
      p0[0]=f2bf(a0.x); p0[1]=f2bf(a0.y); p0[2]=f2bf(a0.z); p0[3]=f2bf(a0.w);
      p0[4]=f2bf(a1.x); p0[5]=f2bf(a1.y); p0[6]=f2bf(a1.z); p0[7]=f2bf(a1.w);
      p1[0]=f2bf(a2.x); p1[1]=f2bf(a2.y); p1[2]=f2bf(a2.z); p1[3]=f2bf(a2.w);
      p1[4]=f2bf(a3.x); p1[5]=f2bf(a3.y); p1[6]=f2bf(a3.z); p1[7]=f2bf(a3.w);
      *(us8*)&As[srow][skc]     = p0;
      *(us8*)&As[srow][skc + 8] = p1;
      *(us8*)&Bs[srow][skc]     = b0;
      *(us8*)&Bs[srow][skc + 8] = b1;
    }
    if (k0 + 32 < EMB) {  // issue next-tile loads; latency hides under MFMA
      const float* An = Aaddr + k0 + 32;
      a0 = *(const float4*)(An);
      a1 = *(const float4*)(An + 4);
      a2 = *(const float4*)(An + 8);
      a3 = *(const float4*)(An + 12);
      const unsigned short* Bn = Baddr + k0 + 32;
      b0 = *(const us8*)(Bn);
      b1 = *(const us8*)(Bn + 8);
    }
    __syncthreads();  // tile ready

    bf16x8 av[4], bv_[4];
#pragma unroll
    for (int mi = 0; mi < 4; ++mi) av[mi]  = *(const bf16x8*)&As[wrb + mi*16 + r16][kq];
#pragma unroll
    for (int ni = 0; ni < 4; ++ni) bv_[ni] = *(const bf16x8*)&Bs[wcb + ni*16 + r16][kq];
#pragma unroll
    for (int mi = 0; mi < 4; ++mi)
#pragma unroll
      for (int ni = 0; ni < 4; ++ni)
        acc[mi][ni] = mfma16(av[mi], bv_[ni], acc[mi][ni]);
  }

#pragma unroll
  for (int ni = 0; ni < 4; ++ni) {
    const long col = bcol + wcb + ni*16 + r16;
    const float bval = bias[col];
#pragma unroll
    for (int mi = 0; mi < 4; ++mi)
#pragma unroll
      for (int jr = 0; jr < 4; ++jr) {
        const long row = brow + wrb + mi*16 + rq + jr;
        const float v = acc[mi][ni][jr] + bval;
        if (z == 2) {
          long r = row;
          if (col >= 512) {
            const long seg = row >> 12;
            const long p = row & 4095;
            r = (seg << 12) + ((p & 1) ? (p >> 1) : 2048 + (p >> 1));
          }
          O2[col * (long)N_TOK + r] = f2bf(v);
        } else {
          unsigned short* O = (z == 0) ? O0 : O1;
          O[row * (long)EMB + col] = f2bf(v);
        }
      }
  }
}

// ---------------- merged dilated flash attention (unchanged from R3) ----------------
__global__ __launch_bounds__(256) void attn_dilated2(
    const unsigned short* __restrict__ Qp, const unsigned short* __restrict__ Kp,
    const unsigned short* __restrict__ Vt, unsigned short* __restrict__ AO)
{
  __shared__ __align__(16) unsigned short Ks[64][72];
  __shared__ __align__(16) unsigned short Vs[64][72];   // Vs[d][key]
  __shared__ __align__(16) unsigned short Ps[128][72];

  const int z   = blockIdx.z;
  const int g1  = (z >= 4);
  const int dil = g1 ? 2 : 1;
  const int off = g1 ? 1 : 0;
  const long segb = g1 ? (long)(z - 4) * 4096 : (long)z * 2048;
  const int h   = (g1 ? 8 : 0) + blockIdx.y;
  const int h64 = h * 64;

  const int qtile = 15 - (int)blockIdx.x;
  const int tid  = threadIdx.x;
  const int lane = tid & 63;
  const int wv   = tid >> 6;
  const int r16  = lane & 15;
  const int kq   = (lane >> 4) * 8;
  const int rq   = (lane >> 4) * 4;

  bf16x8 aq[2][2];
#pragma unroll
  for (int mi = 0; mi < 2; ++mi) {
    const long grow = segb + off + (long)dil * (qtile * 128 + wv * 32 + mi * 16 + r16);
    const unsigned short* qsrc = Qp + grow * EMB + h64;
    aq[mi][0] = *(const bf16x8*)(qsrc + kq);
    aq[mi][1] = *(const bf16x8*)(qsrc + 32 + kq);
  }

  const f32x4 zz = {0.f, 0.f, 0.f, 0.f};
  f32x4 o_acc[2][4];
  float m_run[2][4], l_run[2][4];
#pragma unroll
  for (int mi = 0; mi < 2; ++mi)
#pragma unroll
    for (int t = 0; t < 4; ++t) {
      o_acc[mi][t] = zz;
      m_run[mi][t] = -1e30f;
      l_run[mi][t] = 0.f;
    }

  const int srow = tid >> 2;
  const int scs  = (tid & 3) * 16;
  const int jmax = 2 * qtile + 1;

  for (int j = 0; j <= jmax; ++j) {
    __syncthreads();
    {
      const long gk = segb + off + (long)dil * (j * 64 + srow);
      const unsigned short* ksrc = Kp + gk * EMB + h64 + scs;
      *(us8*)&Ks[srow][scs]     = *(const us8*)ksrc;
      *(us8*)&Ks[srow][scs + 8] = *(const us8*)(ksrc + 8);
      const unsigned short* vsrc = Vt + (long)(h64 + srow) * N_TOK + segb + j * 64 + scs;
      *(us8*)&Vs[srow][scs]     = *(const us8*)vsrc;
      *(us8*)&Vs[srow][scs + 8] = *(const us8*)(vsrc + 8);
    }
    __syncthreads();

    const bool diagz = (j >= 2 * qtile);
#pragma unroll
    for (int mi = 0; mi < 2; ++mi) {
      f32x4 st[4];
#pragma unroll
      for (int nt = 0; nt < 4; ++nt) {
        bf16x8 bk0 = *(const bf16x8*)&Ks[nt*16 + r16][kq];
        bf16x8 bk1 = *(const bf16x8*)&Ks[nt*16 + r16][32 + kq];
        st[nt] = mfma16(aq[mi][1], bk1, mfma16(aq[mi][0], bk0, zz));
      }

#pragma unroll
      for (int nt = 0; nt < 4; ++nt)
#pragma unroll
        for (int jr = 0; jr < 4; ++jr) {
          float v = st[nt][jr] * 0.125f;
          if (diagz && (j*64 + nt*16 + r16 > qtile*128 + wv*32 + mi*16 + rq + jr))
            v = -1e30f;
          st[nt][jr] = v;
        }

#pragma unroll
      for (int jr = 0; jr < 4; ++jr) {
        float mx = fmaxf(fmaxf(st[0][jr], st[1][jr]), fmaxf(st[2][jr], st[3][jr]));
#pragma unroll
        for (int sm = 1; sm < 16; sm <<= 1) mx = fmaxf(mx, __shfl_xor(mx, sm, 64));
        const float mnew  = fmaxf(m_run[mi][jr], mx);
        const float alpha = __expf(m_run[mi][jr] - mnew);
        float psum = 0.f;
#pragma unroll
        for (int nt = 0; nt < 4; ++nt) {
          const float p = __expf(st[nt][jr] - mnew);
          st[nt][jr] = p;
          psum += p;
        }
#pragma unroll
        for (int sm = 1; sm < 16; sm <<= 1) psum += __shfl_xor(psum, sm, 64);
        l_run[mi][jr] = l_run[mi][jr] * alpha + psum;
        m_run[mi][jr] = mnew;
#pragma unroll
        for (int dt = 0; dt < 4; ++dt) o_acc[mi][dt][jr] *= alpha;
      }

#pragma unroll
      for (int nt = 0; nt < 4; ++nt)
#pragma unroll
        for (int jr = 0; jr < 4; ++jr)
          Ps[wv*32 + mi*16 + rq + jr][nt*16 + r16] = f2bf(st[nt][jr]);
    }

#pragma unroll
    for (int mi = 0; mi < 2; ++mi)
#pragma unroll
      for (int kk = 0; kk < 2; ++kk) {
        bf16x8 pa = *(const bf16x8*)&Ps[wv*32 + mi*16 + r16][kk*32 + kq];
#pragma unroll
        for (int dt = 0; dt < 4; ++dt) {
          bf16x8 vb = *(const bf16x8*)&Vs[dt*16 + r16][kk*32 + kq];
          o_acc[mi][dt] = mfma16(pa, vb, o_acc[mi][dt]);
        }
      }
  }

#pragma unroll
  for (int mi = 0; mi < 2; ++mi)
#pragma unroll
    for (int jr = 0; jr < 4; ++jr) {
      const float inv = 1.f / l_run[mi][jr];
      const int row_l = wv*32 + mi*16 + rq + jr;
      const long grow = segb + off + (long)dil * (qtile*128 + row_l);
      unsigned short* dst = AO + grow * EMB + h64 + r16;
#pragma unroll
      for (int dt = 0; dt < 4; ++dt)
        dst[dt*16] = f2bf(o_acc[mi][dt][jr] * inv);
    }
}

// ---------------- output projection (A bf16, W bf16, prefetched) ----------------
__global__ __launch_bounds__(256) void gemm_out2(
    const unsigned short* __restrict__ A, const unsigned short* __restrict__ Wb,
    const float* __restrict__ bias, float* __restrict__ outp)
{
  __shared__ __align__(16) unsigned short As[128][40];
  __shared__ __align__(16) unsigned short Bs[128][40];

  const int lin  = blockIdx.x;
  const int work = (lin & 7) * 64 + (lin >> 3);
  const long brow = (long)(work >> 3) * 128;
  const long bcol = (long)(work & 7) * 128;

  const int tid  = threadIdx.x;
  const int lane = tid & 63;
  const int wv   = tid >> 6;
  const int wrb  = (wv >> 1) * 64;
  const int wcb  = (wv & 1) * 64;

  const int srow = tid >> 1;
  const int skc  = (tid & 1) * 16;
  const int r16  = lane & 15;
  const int kq   = (lane >> 4) * 8;
  const int rq   = (lane >> 4) * 4;

  const unsigned short* Aaddr = A  + (brow + srow) * (long)EMB + skc;
  const unsigned short* Baddr = Wb + (bcol + srow) * (long)EMB + skc;

  const f32x4 zz = {0.f, 0.f, 0.f, 0.f};
  f32x4 acc[4][4];
#pragma unroll
  for (int i = 0; i < 4; ++i)
#pragma unroll
    for (int j = 0; j < 4; ++j) acc[i][j] = zz;

  us8 a0 = *(const us8*)(Aaddr);
  us8 a1 = *(const us8*)(Aaddr + 8);
  us8 b0 = *(const us8*)(Baddr);
  us8 b1 = *(const us8*)(Baddr + 8);

  for (int k0 = 0; k0 < EMB; k0 += 32) {
    __syncthreads();
    *(us8*)&As[srow][skc]     = a0;
    *(us8*)&As[srow][skc + 8] = a1;
    *(us8*)&Bs[srow][skc]     = b0;
    *(us8*)&Bs[srow][skc + 8] = b1;
    if (k0 + 32 < EMB) {
      a0 = *(const us8*)(Aaddr + k0 + 32);
      a1 = *(const us8*)(Aaddr + k0 + 40);
      b0 = *(const us8*)(Baddr + k0 + 32);
      b1 = *(const us8*)(Baddr + k0 + 40);
    }
    __syncthreads();

    bf16x8 av[4], bv_[4];
#pragma unroll
    for (int mi = 0; mi < 4; ++mi) av[mi]  = *(const bf16x8*)&As[wrb + mi*16 + r16][kq];
#pragma unroll
    for (int ni = 0; ni < 4; ++ni) bv_[ni] = *(const bf16x8*)&Bs[wcb + ni*16 + r16][kq];
#pragma unroll
    for (int mi = 0; mi < 4; ++mi)
#pragma unroll
      for (int ni = 0; ni < 4; ++ni)
        acc[mi][ni] = mfma16(av[mi], bv_[ni], acc[mi][ni]);
  }

#pragma unroll
  for (int ni = 0; ni < 4; ++ni) {
    const long col = bcol + wcb + ni*16 + r16;
    const float bval = bias[col];
#pragma unroll
    for (int mi = 0; mi < 4; ++mi)
#pragma unroll
      for (int jr = 0; jr < 4; ++jr) {
        const long row = brow + wrb + mi*16 + rq + jr;
        outp[row * (long)EMB + col] = acc[mi][ni][jr] + bval;
      }
  }
}

extern "C" void kernel_launch(void* const* d_in, const int* in_sizes, int n_in,
                              void* d_out, int out_size, void* d_ws, size_t ws_size,
                              hipStream_t stream) {
  const float* query = (const float*)d_in[0];
  const float* key_  = (const float*)d_in[1];
  const float* value = (const float*)d_in[2];
  const float* Wq = (const float*)d_in[3];
  const float* bq = (const float*)d_in[4];
  const float* Wk = (const float*)d_in[5];
  const float* bk = (const float*)d_in[6];
  const float* Wv = (const float*)d_in[7];
  const float* bv = (const float*)d_in[8];
  const float* Wo = (const float*)d_in[9];
  const float* bo = (const float*)d_in[10];

  unsigned short* Qp  = (unsigned short*)d_ws;
  unsigned short* Kp  = Qp + (size_t)N_TOK * EMB;
  unsigned short* Vt  = Kp + (size_t)N_TOK * EMB;   // [EMB][N_TOK], group1 token-remapped
  unsigned short* AO  = Vt + (size_t)N_TOK * EMB;
  unsigned short* Wb  = AO + (size_t)N_TOK * EMB;   // Wq,Wk,Wv,Wo bf16 (4 x 2 MiB)
  unsigned short* Wob = Wb + (size_t)3 * EMB * EMB;

  dim3 blk(256);

  hipLaunchKernelGGL(wconv, dim3(EMB*EMB/(256*16), 4), blk, 0, stream,
                     Wq, Wk, Wv, Wo, Wb);

  hipLaunchKernelGGL(qkv_gemm2, dim3(512, 1, 3), blk, 0, stream,
                     query, key_, value, Wb, bq, bk, bv, Qp, Kp, Vt);

  hipMemsetAsync(AO, 0, (size_t)N_TOK * EMB * 2, stream);

  hipLaunchKernelGGL(attn_dilated2, dim3(16, 8, 6), blk, 0, stream, Qp, Kp, Vt, AO);

  hipLaunchKernelGGL(gemm_out2, dim3(512), blk, 0, stream, AO, Wob, bo, (float*)d_out);
}

// Round 5
// 243.071 us; speedup vs baseline: 1.8807x; 1.3077x over previous
//
#include <hip/hip_runtime.h>
#include <hip/hip_bf16.h>

typedef __attribute__((ext_vector_type(8))) __bf16 bf16x8;
typedef __attribute__((ext_vector_type(8))) unsigned short us8;
typedef __attribute__((ext_vector_type(4))) float f32x4;
typedef __attribute__((ext_vector_type(16))) float f32x16;

#define N_TOK 8192
#define EMB 1024

static __device__ __forceinline__ unsigned short f2bf(float f) {
  union { float f; unsigned int u; } c; c.f = f;
  unsigned int u = c.u;
  u = (u + 0x7fffu + ((u >> 16) & 1u)) >> 16;  // RNE
  return (unsigned short)u;
}

static __device__ __forceinline__ f32x4 mfma16(bf16x8 a, bf16x8 b, f32x4 c) {
  return __builtin_amdgcn_mfma_f32_16x16x32_bf16(a, b, c, 0, 0, 0);
}
static __device__ __forceinline__ f32x16 mfma32(bf16x8 a, bf16x8 b, f32x16 c) {
  return __builtin_amdgcn_mfma_f32_32x32x16_bf16(a, b, c, 0, 0, 0);
}
static __device__ __forceinline__ unsigned int cvtpk(float lo, float hi) {
  unsigned int r;
  asm("v_cvt_pk_bf16_f32 %0, %1, %2" : "=v"(r) : "v"(lo), "v"(hi));
  return r;
}

// ---------------- weight fp32 -> bf16 conversion (Wq,Wk,Wv,Wo) ----------------
__global__ __launch_bounds__(256) void wconv(
    const float* __restrict__ W0, const float* __restrict__ W1,
    const float* __restrict__ W2, const float* __restrict__ W3,
    unsigned short* __restrict__ O)
{
  const float* W = (blockIdx.y == 0) ? W0 : (blockIdx.y == 1) ? W1 :
                   (blockIdx.y == 2) ? W2 : W3;
  unsigned short* o = O + (size_t)blockIdx.y * EMB * EMB;
  const int base = (blockIdx.x * 256 + threadIdx.x) * 16;
  float4 f0 = *(const float4*)(W + base);
  float4 f1 = *(const float4*)(W + base + 4);
  float4 f2 = *(const float4*)(W + base + 8);
  float4 f3 = *(const float4*)(W + base + 12);
  us8 p0, p1;
  p0[0]=f2bf(f0.x); p0[1]=f2bf(f0.y); p0[2]=f2bf(f0.z); p0[3]=f2bf(f0.w);
  p0[4]=f2bf(f1.x); p0[5]=f2bf(f1.y); p0[6]=f2bf(f1.z); p0[7]=f2bf(f1.w);
  p1[0]=f2bf(f2.x); p1[1]=f2bf(f2.y); p1[2]=f2bf(f2.z); p1[3]=f2bf(f2.w);
  p1[4]=f2bf(f3.x); p1[5]=f2bf(f3.y); p1[6]=f2bf(f3.z); p1[7]=f2bf(f3.w);
  *(us8*)(o + base)     = p0;
  *(us8*)(o + base + 8) = p1;
}

// ---------------- fused QKV projection (A fp32, W bf16, prefetched) ----------------
__global__ __launch_bounds__(256) void qkv_gemm2(
    const float* __restrict__ Xq, const float* __restrict__ Xk, const float* __restrict__ Xv,
    const unsigned short* __restrict__ Wb,
    const float* __restrict__ bq, const float* __restrict__ bk, const float* __restrict__ bv,
    unsigned short* __restrict__ O0, unsigned short* __restrict__ O1, unsigned short* __restrict__ O2)
{
  __shared__ __align__(16) unsigned short As[128][40];
  __shared__ __align__(16) unsigned short Bs[128][40];

  const int z = blockIdx.z;
  const float* X = (z == 0) ? Xq : (z == 1) ? Xk : Xv;
  const unsigned short* W = Wb + (size_t)z * EMB * EMB;
  const float* bias = (z == 0) ? bq : (z == 1) ? bk : bv;

  const int lin  = blockIdx.x;
  const int work = (lin & 7) * 64 + (lin >> 3);
  const long brow = (long)(work >> 3) * 128;
  const long bcol = (long)(work & 7) * 128;

  const int tid  = threadIdx.x;
  const int lane = tid & 63;
  const int wv   = tid >> 6;
  const int wrb  = (wv >> 1) * 64;
  const int wcb  = (wv & 1) * 64;

  const int srow = tid >> 1;
  const int skc  = (tid & 1) * 16;
  const int r16  = lane & 15;
  const int kq   = (lane >> 4) * 8;
  const int rq   = (lane >> 4) * 4;

  const float* Aaddr = X + (brow + srow) * (long)EMB + skc;
  const unsigned short* Baddr = W + (bcol + srow) * (long)EMB + skc;

  const f32x4 zz = {0.f, 0.f, 0.f, 0.f};
  f32x4 acc[4][4];
#pragma unroll
  for (int i = 0; i < 4; ++i)
#pragma unroll
    for (int j = 0; j < 4; ++j) acc[i][j] = zz;

  float4 a0 = *(const float4*)(Aaddr);
  float4 a1 = *(const float4*)(Aaddr + 4);
  float4 a2 = *(const float4*)(Aaddr + 8);
  float4 a3 = *(const float4*)(Aaddr + 12);
  us8 b0 = *(const us8*)(Baddr);
  us8 b1 = *(const us8*)(Baddr + 8);

  for (int k0 = 0; k0 < EMB; k0 += 32) {
    __syncthreads();
    {
      us8 p0, p1;
      p0[0]=f2bf(a0.x); p0[1]=f2bf(a0.y); p0[2]=f2bf(a0.z); p0[3]=f2bf(a0.w);
      p0[4]=f2bf(a1.x); p0[5]=f2bf(a1.y); p0[6]=f2bf(a1.z); p0[7]=f2bf(a1.w);
      p1[0]=f2bf(a2.x); p1[1]=f2bf(a2.y); p1[2]=f2bf(a2.z); p1[3]=f2bf(a2.w);
      p1[4]=f2bf(a3.x); p1[5]=f2bf(a3.y); p1[6]=f2bf(a3.z); p1[7]=f2bf(a3.w);
      *(us8*)&As[srow][skc]     = p0;
      *(us8*)&As[srow][skc + 8] = p1;
      *(us8*)&Bs[srow][skc]     = b0;
      *(us8*)&Bs[srow][skc + 8] = b1;
    }
    if (k0 + 32 < EMB) {
      const float* An = Aaddr + k0 + 32;
      a0 = *(const float4*)(An);
      a1 = *(const float4*)(An + 4);
      a2 = *(const float4*)(An + 8);
      a3 = *(const float4*)(An + 12);
      const unsigned short* Bn = Baddr + k0 + 32;
      b0 = *(const us8*)(Bn);
      b1 = *(const us8*)(Bn + 8);
    }
    __syncthreads();

    bf16x8 av[4], bv_[4];
#pragma unroll
    for (int mi = 0; mi < 4; ++mi) av[mi]  = *(const bf16x8*)&As[wrb + mi*16 + r16][kq];
#pragma unroll
    for (int ni = 0; ni < 4; ++ni) bv_[ni] = *(const bf16x8*)&Bs[wcb + ni*16 + r16][kq];
#pragma unroll
    for (int mi = 0; mi < 4; ++mi)
#pragma unroll
      for (int ni = 0; ni < 4; ++ni)
        acc[mi][ni] = mfma16(av[mi], bv_[ni], acc[mi][ni]);
  }

#pragma unroll
  for (int ni = 0; ni < 4; ++ni) {
    const long col = bcol + wcb + ni*16 + r16;
    const float bval = bias[col];
#pragma unroll
    for (int mi = 0; mi < 4; ++mi)
#pragma unroll
      for (int jr = 0; jr < 4; ++jr) {
        const long row = brow + wrb + mi*16 + rq + jr;
        const float v = acc[mi][ni][jr] + bval;
        if (z == 2) {
          long r = row;
          if (col >= 512) {
            const long seg = row >> 12;
            const long p = row & 4095;
            r = (seg << 12) + ((p & 1) ? (p >> 1) : 2048 + (p >> 1));
          }
          O2[col * (long)N_TOK + r] = f2bf(v);
        } else {
          unsigned short* O = (z == 0) ? O0 : O1;
          O[row * (long)EMB + col] = f2bf(v);
        }
      }
  }
}

// ---------------- dilated flash attention: swapped 32x32 QK^T, in-reg softmax ----------------
// Per block: 4 waves x 32 q-rows = 128-row qtile. KVBLK=64, double-buffered K/V LDS.
// S^T = mfma32(K, Q): lane holds col q = lane&31, rows key = (r&3)+8*(r>>2)+4*(lane>>5) (+32 for kb=1).
// O^T[d][q] accumulated via mfma32(V^T, P^T).
__global__ __launch_bounds__(256) void attn_dilated3(
    const unsigned short* __restrict__ Qp, const unsigned short* __restrict__ Kp,
    const unsigned short* __restrict__ Vt, unsigned short* __restrict__ AO)
{
  __shared__ __align__(16) unsigned short Ks[2][64][72];
  __shared__ __align__(16) unsigned short Vs[2][64][72];   // Vs[buf][d][key]

  const int z   = blockIdx.z;
  const int g1  = (z >= 4);
  const int dil = g1 ? 2 : 1;
  const int off = g1 ? 1 : 0;
  const long segb = g1 ? (long)(z - 4) * 4096 : (long)z * 2048;
  const int h   = (g1 ? 8 : 0) + blockIdx.y;
  const int h64 = h * 64;

  const int t    = 15 - (int)blockIdx.x;   // qtile (128 rows), long blocks first
  const int tid  = threadIdx.x;
  const int lane = tid & 63;
  const int w    = tid >> 6;
  const int q5   = lane & 31;
  const int hh   = lane >> 5;

  const int qq    = t*128 + w*32 + q5;     // local dilated q index
  const long qrow = segb + off + (long)dil * qq;

  // Q fragments (B operand): qf[s] = Q[qq][16s + 8hh .. +7]
  bf16x8 qf[4];
  {
    const unsigned short* qsrc = Qp + qrow * EMB + h64 + 8*hh;
#pragma unroll
    for (int s = 0; s < 4; ++s) qf[s] = *(const bf16x8*)(qsrc + 16*s);
  }

  float m_run = -1e30f, l_run = 0.f;
  f32x16 o0, o1;   // O^T: d = (r&3)+8*(r>>2)+4*hh (+32 for o1), q = q5
#pragma unroll
  for (int r = 0; r < 16; ++r) { o0[r] = 0.f; o1[r] = 0.f; }

  const int srow = tid >> 2;        // staging row (key for Ks, d for Vs)
  const int scs  = (tid & 3) * 16;
  const int jmax = 2*t + 1;
  const int jw   = (t*128 + w*32 + 31) >> 6;   // last tile this wave computes

  us8 kr0, kr1, vr0, vr1;
  // prologue: stage tile 0
  {
    const long gk = segb + off + (long)dil * (0*64 + srow);
    const unsigned short* ksrc = Kp + gk*EMB + h64 + scs;
    kr0 = *(const us8*)ksrc; kr1 = *(const us8*)(ksrc + 8);
    const unsigned short* vsrc = Vt + (long)(h64 + srow)*N_TOK + segb + scs;
    vr0 = *(const us8*)vsrc; vr1 = *(const us8*)(vsrc + 8);
    *(us8*)&Ks[0][srow][scs]   = kr0;
    *(us8*)&Ks[0][srow][scs+8] = kr1;
    *(us8*)&Vs[0][srow][scs]   = vr0;
    *(us8*)&Vs[0][srow][scs+8] = vr1;
  }
  __syncthreads();
  int cur = 0;

  for (int j = 0; j <= jmax; ++j) {
    // issue next-tile global loads early (latency hides under compute)
    if (j < jmax) {
      const long gk = segb + off + (long)dil * ((j+1)*64 + srow);
      const unsigned short* ksrc = Kp + gk*EMB + h64 + scs;
      kr0 = *(const us8*)ksrc; kr1 = *(const us8*)(ksrc + 8);
      const unsigned short* vsrc = Vt + (long)(h64 + srow)*N_TOK + segb + (j+1)*64 + scs;
      vr0 = *(const us8*)vsrc; vr1 = *(const us8*)(vsrc + 8);
    }

    if (j <= jw) {
      // ---- QK^T: S^T[key][q] over 64 keys (2 kb subtiles) ----
      f32x16 sa0, sa1;
#pragma unroll
      for (int r = 0; r < 16; ++r) { sa0[r] = 0.f; sa1[r] = 0.f; }
      __builtin_amdgcn_s_setprio(1);
#pragma unroll
      for (int s = 0; s < 4; ++s) {
        bf16x8 ka = *(const bf16x8*)&Ks[cur][q5][16*s + 8*hh];
        sa0 = mfma32(ka, qf[s], sa0);
      }
#pragma unroll
      for (int s = 0; s < 4; ++s) {
        bf16x8 kb = *(const bf16x8*)&Ks[cur][32 + q5][16*s + 8*hh];
        sa1 = mfma32(kb, qf[s], sa1);
      }
      __builtin_amdgcn_s_setprio(0);

      const bool do_kb1 = (j*64 + 32 <= t*128 + w*32 + 31);
      const bool diag   = (j*64 + 63 > t*128 + w*32);

      // ---- scale + causal mask + row max (in-register) ----
      float sv[32];
      float mloc = -1e30f;
#pragma unroll
      for (int r = 0; r < 16; ++r) {
        const int kof = (r&3) + 8*(r>>2);
        float v = sa0[r] * 0.125f;
        if (diag && (j*64 + kof + 4*hh > qq)) v = -1e30f;
        sv[r] = v; mloc = fmaxf(mloc, v);
      }
      if (do_kb1) {
#pragma unroll
        for (int r = 0; r < 16; ++r) {
          const int kof = (r&3) + 8*(r>>2);
          float v = sa1[r] * 0.125f;
          if (diag && (j*64 + 32 + kof + 4*hh > qq)) v = -1e30f;
          sv[16+r] = v; mloc = fmaxf(mloc, v);
        }
      }
      mloc = fmaxf(mloc, __shfl_xor(mloc, 32, 64));

      // ---- online softmax update (all per-lane scalars) ----
      const float mnew  = fmaxf(m_run, mloc);
      const float alpha = __expf(m_run - mnew);
      float psum = 0.f;
#pragma unroll
      for (int i = 0; i < 16; ++i) { float e = __expf(sv[i] - mnew); sv[i] = e; psum += e; }
      if (do_kb1) {
#pragma unroll
        for (int i = 16; i < 32; ++i) { float e = __expf(sv[i] - mnew); sv[i] = e; psum += e; }
      }
      psum += __shfl_xor(psum, 32, 64);
      l_run = l_run * alpha + psum;
      m_run = mnew;
#pragma unroll
      for (int r = 0; r < 16; ++r) { o0[r] *= alpha; o1[r] *= alpha; }

      // ---- P^T frags (cvt_pk + xor-32 exchange) + PV ----
#pragma unroll
      for (int ks = 0; ks < 4; ++ks) {
        if (ks >= 2 && !do_kb1) continue;
        const unsigned int pk0 = cvtpk(sv[8*ks+0], sv[8*ks+1]);
        const unsigned int pk1 = cvtpk(sv[8*ks+2], sv[8*ks+3]);
        const unsigned int pk2 = cvtpk(sv[8*ks+4], sv[8*ks+5]);
        const unsigned int pk3 = cvtpk(sv[8*ks+6], sv[8*ks+7]);
        const unsigned int snd_lo = hh ? pk0 : pk2;
        const unsigned int snd_hi = hh ? pk1 : pk3;
        const unsigned int rcv_lo = (unsigned int)__shfl_xor((int)snd_lo, 32, 64);
        const unsigned int rcv_hi = (unsigned int)__shfl_xor((int)snd_hi, 32, 64);
        union { unsigned int wd[4]; bf16x8 v; } pu;
        pu.wd[0] = hh ? rcv_lo : pk0;
        pu.wd[1] = hh ? rcv_hi : pk1;
        pu.wd[2] = hh ? pk2 : rcv_lo;
        pu.wd[3] = hh ? pk3 : rcv_hi;
        __builtin_amdgcn_s_setprio(1);
        bf16x8 va = *(const bf16x8*)&Vs[cur][q5][16*ks + 8*hh];
        o0 = mfma32(va, pu.v, o0);
        bf16x8 vb = *(const bf16x8*)&Vs[cur][32 + q5][16*ks + 8*hh];
        o1 = mfma32(vb, pu.v, o1);
        __builtin_amdgcn_s_setprio(0);
      }
    }

    // write-late: next tile into the other buffer
    if (j < jmax) {
      *(us8*)&Ks[cur^1][srow][scs]   = kr0;
      *(us8*)&Ks[cur^1][srow][scs+8] = kr1;
      *(us8*)&Vs[cur^1][srow][scs]   = vr0;
      *(us8*)&Vs[cur^1][srow][scs+8] = vr1;
    }
    __syncthreads();
    cur ^= 1;
  }

  // ---- epilogue: O[q][d] = O^T / l ----
  {
    const float inv = 1.f / l_run;
    unsigned short* dst = AO + qrow * EMB + h64;
#pragma unroll
    for (int r = 0; r < 16; ++r) {
      const int d = (r&3) + 8*(r>>2) + 4*hh;
      dst[d]      = f2bf(o0[r] * inv);
      dst[32 + d] = f2bf(o1[r] * inv);
    }
  }
}

// ---------------- output projection (A bf16, W bf16, prefetched) ----------------
__global__ __launch_bounds__(256) void gemm_out2(
    const unsigned short* __restrict__ A, const unsigned short* __restrict__ Wb,
    const float* __restrict__ bias, float* __restrict__ outp)
{
  __shared__ __align__(16) unsigned short As[128][40];
  __shared__ __align__(16) unsigned short Bs[128][40];

  const int lin  = blockIdx.x;
  const int work = (lin & 7) * 64 + (lin >> 3);
  const long brow = (long)(work >> 3) * 128;
  const long bcol = (long)(work & 7) * 128;

  const int tid  = threadIdx.x;
  const int lane = tid & 63;
  const int wv   = tid >> 6;
  const int wrb  = (wv >> 1) * 64;
  const int wcb  = (wv & 1) * 64;

  const int srow = tid >> 1;
  const int skc  = (tid & 1) * 16;
  const int r16  = lane & 15;
  const int kq   = (lane >> 4) * 8;
  const int rq   = (lane >> 4) * 4;

  const unsigned short* Aaddr = A  + (brow + srow) * (long)EMB + skc;
  const unsigned short* Baddr = Wb + (bcol + srow) * (long)EMB + skc;

  const f32x4 zz = {0.f, 0.f, 0.f, 0.f};
  f32x4 acc[4][4];
#pragma unroll
  for (int i = 0; i < 4; ++i)
#pragma unroll
    for (int j = 0; j < 4; ++j) acc[i][j] = zz;

  us8 a0 = *(const us8*)(Aaddr);
  us8 a1 = *(const us8*)(Aaddr + 8);
  us8 b0 = *(const us8*)(Baddr);
  us8 b1 = *(const us8*)(Baddr + 8);

  for (int k0 = 0; k0 < EMB; k0 += 32) {
    __syncthreads();
    *(us8*)&As[srow][skc]     = a0;
    *(us8*)&As[srow][skc + 8] = a1;
    *(us8*)&Bs[srow][skc]     = b0;
    *(us8*)&Bs[srow][skc + 8] = b1;
    if (k0 + 32 < EMB) {
      a0 = *(const us8*)(Aaddr + k0 + 32);
      a1 = *(const us8*)(Aaddr + k0 + 40);
      b0 = *(const us8*)(Baddr + k0 + 32);
      b1 = *(const us8*)(Baddr + k0 + 40);
    }
    __syncthreads();

    bf16x8 av[4], bv_[4];
#pragma unroll
    for (int mi = 0; mi < 4; ++mi) av[mi]  = *(const bf16x8*)&As[wrb + mi*16 + r16][kq];
#pragma unroll
    for (int ni = 0; ni < 4; ++ni) bv_[ni] = *(const bf16x8*)&Bs[wcb + ni*16 + r16][kq];
#pragma unroll
    for (int mi = 0; mi < 4; ++mi)
#pragma unroll
      for (int ni = 0; ni < 4; ++ni)
        acc[mi][ni] = mfma16(av[mi], bv_[ni], acc[mi][ni]);
  }

#pragma unroll
  for (int ni = 0; ni < 4; ++ni) {
    const long col = bcol + wcb + ni*16 + r16;
    const float bval = bias[col];
#pragma unroll
    for (int mi = 0; mi < 4; ++mi)
#pragma unroll
      for (int jr = 0; jr < 4; ++jr) {
        const long row = brow + wrb + mi*16 + rq + jr;
        outp[row * (long)EMB + col] = acc[mi][ni][jr] + bval;
      }
  }
}

extern "C" void kernel_launch(void* const* d_in, const int* in_sizes, int n_in,
                              void* d_out, int out_size, void* d_ws, size_t ws_size,
                              hipStream_t stream) {
  const float* query = (const float*)d_in[0];
  const float* key_  = (const float*)d_in[1];
  const float* value = (const float*)d_in[2];
  const float* Wq = (const float*)d_in[3];
  const float* bq = (const float*)d_in[4];
  const float* Wk = (const float*)d_in[5];
  const float* bk = (const float*)d_in[6];
  const float* Wv = (const float*)d_in[7];
  const float* bv = (const float*)d_in[8];
  const float* Wo = (const float*)d_in[9];
  const float* bo = (const float*)d_in[10];

  unsigned short* Qp  = (unsigned short*)d_ws;
  unsigned short* Kp  = Qp + (size_t)N_TOK * EMB;
  unsigned short* Vt  = Kp + (size_t)N_TOK * EMB;   // [EMB][N_TOK], group1 token-remapped
  unsigned short* AO  = Vt + (size_t)N_TOK * EMB;
  unsigned short* Wb  = AO + (size_t)N_TOK * EMB;   // Wq,Wk,Wv,Wo bf16
  unsigned short* Wob = Wb + (size_t)3 * EMB * EMB;

  dim3 blk(256);

  hipLaunchKernelGGL(wconv, dim3(EMB*EMB/(256*16), 4), blk, 0, stream,
                     Wq, Wk, Wv, Wo, Wb);

  hipLaunchKernelGGL(qkv_gemm2, dim3(512, 1, 3), blk, 0, stream,
                     query, key_, value, Wb, bq, bk, bv, Qp, Kp, Vt);

  hipMemsetAsync(AO, 0, (size_t)N_TOK * EMB * 2, stream);

  hipLaunchKernelGGL(attn_dilated3, dim3(16, 8, 6), blk, 0, stream, Qp, Kp, Vt, AO);

  hipLaunchKernelGGL(gemm_out2, dim3(512), blk, 0, stream, AO, Wob, bo, (float*)d_out);
}

// Round 6
// 232.929 us; speedup vs baseline: 1.9626x; 1.0435x over previous
//
#include <hip/hip_runtime.h>
#include <hip/hip_bf16.h>

typedef __attribute__((ext_vector_type(8))) __bf16 bf16x8;
typedef __attribute__((ext_vector_type(8))) unsigned short us8;
typedef __attribute__((ext_vector_type(4))) float f32x4;
typedef __attribute__((ext_vector_type(16))) float f32x16;

#define N_TOK 8192
#define EMB 1024

static __device__ __forceinline__ unsigned short f2bf(float f) {
  union { __bf16 b; unsigned short u; } c;
  c.b = (__bf16)f;               // compiler emits v_cvt_pk_bf16_f32 pairs
  return c.u;
}

static __device__ __forceinline__ f32x4 mfma16(bf16x8 a, bf16x8 b, f32x4 c) {
  return __builtin_amdgcn_mfma_f32_16x16x32_bf16(a, b, c, 0, 0, 0);
}
static __device__ __forceinline__ f32x16 mfma32(bf16x8 a, bf16x8 b, f32x16 c) {
  return __builtin_amdgcn_mfma_f32_32x32x16_bf16(a, b, c, 0, 0, 0);
}
static __device__ __forceinline__ unsigned int cvtpk(float lo, float hi) {
  unsigned int r;
  asm("v_cvt_pk_bf16_f32 %0, %1, %2" : "=v"(r) : "v"(lo), "v"(hi));
  return r;
}

// ---------------- weight fp32 -> bf16 conversion (Wq,Wk,Wv,Wo) ----------------
__global__ __launch_bounds__(256) void wconv(
    const float* __restrict__ W0, const float* __restrict__ W1,
    const float* __restrict__ W2, const float* __restrict__ W3,
    unsigned short* __restrict__ O)
{
  const float* W = (blockIdx.y == 0) ? W0 : (blockIdx.y == 1) ? W1 :
                   (blockIdx.y == 2) ? W2 : W3;
  unsigned short* o = O + (size_t)blockIdx.y * EMB * EMB;
  const int base = (blockIdx.x * 256 + threadIdx.x) * 16;
  float4 f0 = *(const float4*)(W + base);
  float4 f1 = *(const float4*)(W + base + 4);
  float4 f2 = *(const float4*)(W + base + 8);
  float4 f3 = *(const float4*)(W + base + 12);
  us8 p0, p1;
  p0[0]=f2bf(f0.x); p0[1]=f2bf(f0.y); p0[2]=f2bf(f0.z); p0[3]=f2bf(f0.w);
  p0[4]=f2bf(f1.x); p0[5]=f2bf(f1.y); p0[6]=f2bf(f1.z); p0[7]=f2bf(f1.w);
  p1[0]=f2bf(f2.x); p1[1]=f2bf(f2.y); p1[2]=f2bf(f2.z); p1[3]=f2bf(f2.w);
  p1[4]=f2bf(f3.x); p1[5]=f2bf(f3.y); p1[6]=f2bf(f3.z); p1[7]=f2bf(f3.w);
  *(us8*)(o + base)     = p0;
  *(us8*)(o + base + 8) = p1;
}

// ---------------- fused QKV projection: dbuf LDS, 1 barrier/K-step ----------------
__global__ __launch_bounds__(256) void qkv_gemm3(
    const float* __restrict__ Xq, const float* __restrict__ Xk, const float* __restrict__ Xv,
    const unsigned short* __restrict__ Wb,
    const float* __restrict__ bq, const float* __restrict__ bk, const float* __restrict__ bv,
    unsigned short* __restrict__ O0, unsigned short* __restrict__ O1, unsigned short* __restrict__ O2)
{
  __shared__ __align__(16) unsigned short As[2][128][40];
  __shared__ __align__(16) unsigned short Bs[2][128][40];

  const int z = blockIdx.z;
  const float* X = (z == 0) ? Xq : (z == 1) ? Xk : Xv;
  const unsigned short* W = Wb + (size_t)z * EMB * EMB;
  const float* bias = (z == 0) ? bq : (z == 1) ? bk : bv;

  // bijective XCD-chunked swizzle (8x8 block-tile per XCD)
  const int lin  = blockIdx.x;
  const int work = (lin & 7) * 64 + (lin >> 3);
  const long brow = (long)(work >> 3) * 128;
  const long bcol = (long)(work & 7) * 128;

  const int tid  = threadIdx.x;
  const int lane = tid & 63;
  const int wv   = tid >> 6;
  const int wrb  = (wv >> 1) * 64;
  const int wcb  = (wv & 1) * 64;

  const int srow = tid >> 1;
  const int skc  = (tid & 1) * 16;
  const int r16  = lane & 15;
  const int kq   = (lane >> 4) * 8;
  const int rq   = (lane >> 4) * 4;

  const float* Aaddr = X + (brow + srow) * (long)EMB + skc;
  const unsigned short* Baddr = W + (bcol + srow) * (long)EMB + skc;

  const f32x4 zz = {0.f, 0.f, 0.f, 0.f};
  f32x4 acc[4][4];
#pragma unroll
  for (int i = 0; i < 4; ++i)
#pragma unroll
    for (int j = 0; j < 4; ++j) acc[i][j] = zz;

  // prefetch tile 0
  float4 a0 = *(const float4*)(Aaddr);
  float4 a1 = *(const float4*)(Aaddr + 4);
  float4 a2 = *(const float4*)(Aaddr + 8);
  float4 a3 = *(const float4*)(Aaddr + 12);
  us8 b0 = *(const us8*)(Baddr);
  us8 b1 = *(const us8*)(Baddr + 8);

  int p = 0;
  for (int k0 = 0; k0 < EMB; k0 += 32) {
    // stage current regs -> LDS buf p (iter k+2's reuse of p is fenced by iter k+1's barrier)
    {
      us8 p0, p1;
      p0[0]=f2bf(a0.x); p0[1]=f2bf(a0.y); p0[2]=f2bf(a0.z); p0[3]=f2bf(a0.w);
      p0[4]=f2bf(a1.x); p0[5]=f2bf(a1.y); p0[6]=f2bf(a1.z); p0[7]=f2bf(a1.w);
      p1[0]=f2bf(a2.x); p1[1]=f2bf(a2.y); p1[2]=f2bf(a2.z); p1[3]=f2bf(a2.w);
      p1[4]=f2bf(a3.x); p1[5]=f2bf(a3.y); p1[6]=f2bf(a3.z); p1[7]=f2bf(a3.w);
      *(us8*)&As[p][srow][skc]     = p0;
      *(us8*)&As[p][srow][skc + 8] = p1;
      *(us8*)&Bs[p][srow][skc]     = b0;
      *(us8*)&Bs[p][srow][skc + 8] = b1;
    }
    if (k0 + 32 < EMB) {   // issue next-tile loads; latency hides under MFMA below
      const float* An = Aaddr + k0 + 32;
      a0 = *(const float4*)(An);
      a1 = *(const float4*)(An + 4);
      a2 = *(const float4*)(An + 8);
      a3 = *(const float4*)(An + 12);
      const unsigned short* Bn = Baddr + k0 + 32;
      b0 = *(const us8*)(Bn);
      b1 = *(const us8*)(Bn + 8);
    }
    __syncthreads();   // buf p ready

    bf16x8 av[4], bv_[4];
#pragma unroll
    for (int mi = 0; mi < 4; ++mi) av[mi]  = *(const bf16x8*)&As[p][wrb + mi*16 + r16][kq];
#pragma unroll
    for (int ni = 0; ni < 4; ++ni) bv_[ni] = *(const bf16x8*)&Bs[p][wcb + ni*16 + r16][kq];
#pragma unroll
    for (int mi = 0; mi < 4; ++mi)
#pragma unroll
      for (int ni = 0; ni < 4; ++ni)
        acc[mi][ni] = mfma16(av[mi], bv_[ni], acc[mi][ni]);
    p ^= 1;
  }

#pragma unroll
  for (int ni = 0; ni < 4; ++ni) {
    const long col = bcol + wcb + ni*16 + r16;
    const float bval = bias[col];
#pragma unroll
    for (int mi = 0; mi < 4; ++mi)
#pragma unroll
      for (int jr = 0; jr < 4; ++jr) {
        const long row = brow + wrb + mi*16 + rq + jr;
        const float v = acc[mi][ni][jr] + bval;
        if (z == 2) {
          long r = row;
          if (col >= 512) {   // group-1 heads: odd tokens first within each 4096-seg
            const long seg = row >> 12;
            const long pp = row & 4095;
            r = (seg << 12) + ((pp & 1) ? (pp >> 1) : 2048 + (pp >> 1));
          }
          O2[col * (long)N_TOK + r] = f2bf(v);
        } else {
          unsigned short* O = (z == 0) ? O0 : O1;
          O[row * (long)EMB + col] = f2bf(v);
        }
      }
  }
}

// ---------------- dilated flash attention (unchanged from R5) ----------------
__global__ __launch_bounds__(256) void attn_dilated3(
    const unsigned short* __restrict__ Qp, const unsigned short* __restrict__ Kp,
    const unsigned short* __restrict__ Vt, unsigned short* __restrict__ AO)
{
  __shared__ __align__(16) unsigned short Ks[2][64][72];
  __shared__ __align__(16) unsigned short Vs[2][64][72];   // Vs[buf][d][key]

  const int z   = blockIdx.z;
  const int g1  = (z >= 4);
  const int dil = g1 ? 2 : 1;
  const int off = g1 ? 1 : 0;
  const long segb = g1 ? (long)(z - 4) * 4096 : (long)z * 2048;
  const int h   = (g1 ? 8 : 0) + blockIdx.y;
  const int h64 = h * 64;

  const int t    = 15 - (int)blockIdx.x;
  const int tid  = threadIdx.x;
  const int lane = tid & 63;
  const int w    = tid >> 6;
  const int q5   = lane & 31;
  const int hh   = lane >> 5;

  const int qq    = t*128 + w*32 + q5;
  const long qrow = segb + off + (long)dil * qq;

  bf16x8 qf[4];
  {
    const unsigned short* qsrc = Qp + qrow * EMB + h64 + 8*hh;
#pragma unroll
    for (int s = 0; s < 4; ++s) qf[s] = *(const bf16x8*)(qsrc + 16*s);
  }

  float m_run = -1e30f, l_run = 0.f;
  f32x16 o0, o1;
#pragma unroll
  for (int r = 0; r < 16; ++r) { o0[r] = 0.f; o1[r] = 0.f; }

  const int srow = tid >> 2;
  const int scs  = (tid & 3) * 16;
  const int jmax = 2*t + 1;
  const int jw   = (t*128 + w*32 + 31) >> 6;

  us8 kr0, kr1, vr0, vr1;
  {
    const long gk = segb + off + (long)dil * (0*64 + srow);
    const unsigned short* ksrc = Kp + gk*EMB + h64 + scs;
    kr0 = *(const us8*)ksrc; kr1 = *(const us8*)(ksrc + 8);
    const unsigned short* vsrc = Vt + (long)(h64 + srow)*N_TOK + segb + scs;
    vr0 = *(const us8*)vsrc; vr1 = *(const us8*)(vsrc + 8);
    *(us8*)&Ks[0][srow][scs]   = kr0;
    *(us8*)&Ks[0][srow][scs+8] = kr1;
    *(us8*)&Vs[0][srow][scs]   = vr0;
    *(us8*)&Vs[0][srow][scs+8] = vr1;
  }
  __syncthreads();
  int cur = 0;

  for (int j = 0; j <= jmax; ++j) {
    if (j < jmax) {
      const long gk = segb + off + (long)dil * ((j+1)*64 + srow);
      const unsigned short* ksrc = Kp + gk*EMB + h64 + scs;
      kr0 = *(const us8*)ksrc; kr1 = *(const us8*)(ksrc + 8);
      const unsigned short* vsrc = Vt + (long)(h64 + srow)*N_TOK + segb + (j+1)*64 + scs;
      vr0 = *(const us8*)vsrc; vr1 = *(const us8*)(vsrc + 8);
    }

    if (j <= jw) {
      f32x16 sa0, sa1;
#pragma unroll
      for (int r = 0; r < 16; ++r) { sa0[r] = 0.f; sa1[r] = 0.f; }
      __builtin_amdgcn_s_setprio(1);
#pragma unroll
      for (int s = 0; s < 4; ++s) {
        bf16x8 ka = *(const bf16x8*)&Ks[cur][q5][16*s + 8*hh];
        sa0 = mfma32(ka, qf[s], sa0);
      }
#pragma unroll
      for (int s = 0; s < 4; ++s) {
        bf16x8 kb = *(const bf16x8*)&Ks[cur][32 + q5][16*s + 8*hh];
        sa1 = mfma32(kb, qf[s], sa1);
      }
      __builtin_amdgcn_s_setprio(0);

      const bool do_kb1 = (j*64 + 32 <= t*128 + w*32 + 31);
      const bool diag   = (j*64 + 63 > t*128 + w*32);

      float sv[32];
      float mloc = -1e30f;
#pragma unroll
      for (int r = 0; r < 16; ++r) {
        const int kof = (r&3) + 8*(r>>2);
        float v = sa0[r] * 0.125f;
        if (diag && (j*64 + kof + 4*hh > qq)) v = -1e30f;
        sv[r] = v; mloc = fmaxf(mloc, v);
      }
      if (do_kb1) {
#pragma unroll
        for (int r = 0; r < 16; ++r) {
          const int kof = (r&3) + 8*(r>>2);
          float v = sa1[r] * 0.125f;
          if (diag && (j*64 + 32 + kof + 4*hh > qq)) v = -1e30f;
          sv[16+r] = v; mloc = fmaxf(mloc, v);
        }
      }
      mloc = fmaxf(mloc, __shfl_xor(mloc, 32, 64));

      const float mnew  = fmaxf(m_run, mloc);
      const float alpha = __expf(m_run - mnew);
      float psum = 0.f;
#pragma unroll
      for (int i = 0; i < 16; ++i) { float e = __expf(sv[i] - mnew); sv[i] = e; psum += e; }
      if (do_kb1) {
#pragma unroll
        for (int i = 16; i < 32; ++i) { float e = __expf(sv[i] - mnew); sv[i] = e; psum += e; }
      }
      psum += __shfl_xor(psum, 32, 64);
      l_run = l_run * alpha + psum;
      m_run = mnew;
#pragma unroll
      for (int r = 0; r < 16; ++r) { o0[r] *= alpha; o1[r] *= alpha; }

#pragma unroll
      for (int ks = 0; ks < 4; ++ks) {
        if (ks >= 2 && !do_kb1) continue;
        const unsigned int pk0 = cvtpk(sv[8*ks+0], sv[8*ks+1]);
        const unsigned int pk1 = cvtpk(sv[8*ks+2], sv[8*ks+3]);
        const unsigned int pk2 = cvtpk(sv[8*ks+4], sv[8*ks+5]);
        const unsigned int pk3 = cvtpk(sv[8*ks+6], sv[8*ks+7]);
        const unsigned int snd_lo = hh ? pk0 : pk2;
        const unsigned int snd_hi = hh ? pk1 : pk3;
        const unsigned int rcv_lo = (unsigned int)__shfl_xor((int)snd_lo, 32, 64);
        const unsigned int rcv_hi = (unsigned int)__shfl_xor((int)snd_hi, 32, 64);
        union { unsigned int wd[4]; bf16x8 v; } pu;
        pu.wd[0] = hh ? rcv_lo : pk0;
        pu.wd[1] = hh ? rcv_hi : pk1;
        pu.wd[2] = hh ? pk2 : rcv_lo;
        pu.wd[3] = hh ? pk3 : rcv_hi;
        __builtin_amdgcn_s_setprio(1);
        bf16x8 va = *(const bf16x8*)&Vs[cur][q5][16*ks + 8*hh];
        o0 = mfma32(va, pu.v, o0);
        bf16x8 vb = *(const bf16x8*)&Vs[cur][32 + q5][16*ks + 8*hh];
        o1 = mfma32(vb, pu.v, o1);
        __builtin_amdgcn_s_setprio(0);
      }
    }

    if (j < jmax) {
      *(us8*)&Ks[cur^1][srow][scs]   = kr0;
      *(us8*)&Ks[cur^1][srow][scs+8] = kr1;
      *(us8*)&Vs[cur^1][srow][scs]   = vr0;
      *(us8*)&Vs[cur^1][srow][scs+8] = vr1;
    }
    __syncthreads();
    cur ^= 1;
  }

  {
    const float inv = 1.f / l_run;
    unsigned short* dst = AO + qrow * EMB + h64;
#pragma unroll
    for (int r = 0; r < 16; ++r) {
      const int d = (r&3) + 8*(r>>2) + 4*hh;
      dst[d]      = f2bf(o0[r] * inv);
      dst[32 + d] = f2bf(o1[r] * inv);
    }
  }
}

// ---------------- output projection: dbuf LDS, 1 barrier/K-step ----------------
__global__ __launch_bounds__(256) void gemm_out3(
    const unsigned short* __restrict__ A, const unsigned short* __restrict__ Wb,
    const float* __restrict__ bias, float* __restrict__ outp)
{
  __shared__ __align__(16) unsigned short As[2][128][40];
  __shared__ __align__(16) unsigned short Bs[2][128][40];

  const int lin  = blockIdx.x;
  const int work = (lin & 7) * 64 + (lin >> 3);
  const long brow = (long)(work >> 3) * 128;
  const long bcol = (long)(work & 7) * 128;

  const int tid  = threadIdx.x;
  const int lane = tid & 63;
  const int wv   = tid >> 6;
  const int wrb  = (wv >> 1) * 64;
  const int wcb  = (wv & 1) * 64;

  const int srow = tid >> 1;
  const int skc  = (tid & 1) * 16;
  const int r16  = lane & 15;
  const int kq   = (lane >> 4) * 8;
  const int rq   = (lane >> 4) * 4;

  const unsigned short* Aaddr = A  + (brow + srow) * (long)EMB + skc;
  const unsigned short* Baddr = Wb + (bcol + srow) * (long)EMB + skc;

  const f32x4 zz = {0.f, 0.f, 0.f, 0.f};
  f32x4 acc[4][4];
#pragma unroll
  for (int i = 0; i < 4; ++i)
#pragma unroll
    for (int j = 0; j < 4; ++j) acc[i][j] = zz;

  us8 a0 = *(const us8*)(Aaddr);
  us8 a1 = *(const us8*)(Aaddr + 8);
  us8 b0 = *(const us8*)(Baddr);
  us8 b1 = *(const us8*)(Baddr + 8);

  int p = 0;
  for (int k0 = 0; k0 < EMB; k0 += 32) {
    *(us8*)&As[p][srow][skc]     = a0;
    *(us8*)&As[p][srow][skc + 8] = a1;
    *(us8*)&Bs[p][srow][skc]     = b0;
    *(us8*)&Bs[p][srow][skc + 8] = b1;
    if (k0 + 32 < EMB) {
      a0 = *(const us8*)(Aaddr + k0 + 32);
      a1 = *(const us8*)(Aaddr + k0 + 40);
      b0 = *(const us8*)(Baddr + k0 + 32);
      b1 = *(const us8*)(Baddr + k0 + 40);
    }
    __syncthreads();

    bf16x8 av[4], bv_[4];
#pragma unroll
    for (int mi = 0; mi < 4; ++mi) av[mi]  = *(const bf16x8*)&As[p][wrb + mi*16 + r16][kq];
#pragma unroll
    for (int ni = 0; ni < 4; ++ni) bv_[ni] = *(const bf16x8*)&Bs[p][wcb + ni*16 + r16][kq];
#pragma unroll
    for (int mi = 0; mi < 4; ++mi)
#pragma unroll
      for (int ni = 0; ni < 4; ++ni)
        acc[mi][ni] = mfma16(av[mi], bv_[ni], acc[mi][ni]);
    p ^= 1;
  }

#pragma unroll
  for (int ni = 0; ni < 4; ++ni) {
    const long col = bcol + wcb + ni*16 + r16;
    const float bval = bias[col];
#pragma unroll
    for (int mi = 0; mi < 4; ++mi)
#pragma unroll
      for (int jr = 0; jr < 4; ++jr) {
        const long row = brow + wrb + mi*16 + rq + jr;
        outp[row * (long)EMB + col] = acc[mi][ni][jr] + bval;
      }
  }
}

extern "C" void kernel_launch(void* const* d_in, const int* in_sizes, int n_in,
                              void* d_out, int out_size, void* d_ws, size_t ws_size,
                              hipStream_t stream) {
  const float* query = (const float*)d_in[0];
  const float* key_  = (const float*)d_in[1];
  const float* value = (const float*)d_in[2];
  const float* Wq = (const float*)d_in[3];
  const float* bq = (const float*)d_in[4];
  const float* Wk = (const float*)d_in[5];
  const float* bk = (const float*)d_in[6];
  const float* Wv = (const float*)d_in[7];
  const float* bv = (const float*)d_in[8];
  const float* Wo = (const float*)d_in[9];
  const float* bo = (const float*)d_in[10];

  unsigned short* Qp  = (unsigned short*)d_ws;
  unsigned short* Kp  = Qp + (size_t)N_TOK * EMB;
  unsigned short* Vt  = Kp + (size_t)N_TOK * EMB;   // [EMB][N_TOK], group1 token-remapped
  unsigned short* AO  = Vt + (size_t)N_TOK * EMB;
  unsigned short* Wb  = AO + (size_t)N_TOK * EMB;   // Wq,Wk,Wv,Wo bf16
  unsigned short* Wob = Wb + (size_t)3 * EMB * EMB;

  dim3 blk(256);

  hipLaunchKernelGGL(wconv, dim3(EMB*EMB/(256*16), 4), blk, 0, stream,
                     Wq, Wk, Wv, Wo, Wb);

  hipLaunchKernelGGL(qkv_gemm3, dim3(512, 1, 3), blk, 0, stream,
                     query, key_, value, Wb, bq, bk, bv, Qp, Kp, Vt);

  hipMemsetAsync(AO, 0, (size_t)N_TOK * EMB * 2, stream);

  hipLaunchKernelGGL(attn_dilated3, dim3(16, 8, 6), blk, 0, stream, Qp, Kp, Vt, AO);

  hipLaunchKernelGGL(gemm_out3, dim3(512), blk, 0, stream, AO, Wob, bo, (float*)d_out);
}